// Round 4
// baseline (68.612 us; speedup 1.0000x reference)
//
#include <hip/hip_runtime.h>

#define BATCH 4096
#define CLEN  8192
#define COEF  0.1f
#define NT    256

// Fixed-point packing for the single-atomic cross-block reduce:
//   bits [0,44):  sum of round(partial * 2^20)  (max ~5.4e11, 32x headroom)
//   bits [44,..): arrival count (each block adds 1<<44)
#define FIX_SCALE 1048576.0f   // 2^20
#define CNT_SHIFT 44
#define VAL_MASK  ((1ULL << CNT_SHIFT) - 1ULL)

// Tiny graph node replacing hipMemsetAsync (fill node costs ~40-75 us!).
// Device-scope atomic store so the next kernel's atomics (which go to the
// device coherence point) are ordered with it across XCDs.
__global__ void dfal_zero_kernel(unsigned long long* __restrict__ acc64) {
    __hip_atomic_store(acc64, 0ULL, __ATOMIC_RELAXED, __HIP_MEMORY_SCOPE_AGENT);
}

// One block per row. partial_b = inv_norm(t_b) * sum_i |i - t_b| * exp(x[b,i]).
// Cross-block combine via ONE packed integer atomic: integer adds commute
// exactly -> bitwise-deterministic; the block whose add completes the count
// holds the full total in (old value field + its own contribution).
__global__ __launch_bounds__(NT) void dfal_fused2_kernel(
    const float* __restrict__ in,
    const int*   __restrict__ target,
    unsigned long long* __restrict__ acc64,
    float*       __restrict__ out)
{
    const int b   = blockIdx.x;
    const int tid = threadIdx.x;

    const long long t = (long long)target[b];
    // Exact sum of squared distances sum_{i=0}^{C-1} (i-t)^2, closed form.
    const long long m  = (long long)(CLEN - 1) - t;
    const long long ss = t * (t + 1) * (2 * t + 1) / 6
                       + m * (m + 1) * (2 * m + 1) / 6;
    const float inv_norm = (t == 0) ? 0.0f : (float)(1.0 / sqrt((double)ss));

    const float4* __restrict__ in4 = (const float4*)(in + (size_t)b * CLEN);
    const float tf = (float)t;

    float acc = 0.0f;
#pragma unroll
    for (int j = tid; j < CLEN / 4; j += NT) {
        const float4 x = in4[j];
        const float i0 = (float)(4 * j);
        acc = fmaf(fabsf(i0        - tf), __expf(x.x), acc);
        acc = fmaf(fabsf(i0 + 1.0f - tf), __expf(x.y), acc);
        acc = fmaf(fabsf(i0 + 2.0f - tf), __expf(x.z), acc);
        acc = fmaf(fabsf(i0 + 3.0f - tf), __expf(x.w), acc);
    }

    // Wave (64-lane) reduction, then cross-wave via LDS.
#pragma unroll
    for (int off = 32; off; off >>= 1) acc += __shfl_down(acc, off, 64);

    __shared__ float wsum[NT / 64];
    if ((tid & 63) == 0) wsum[tid >> 6] = acc;
    __syncthreads();

    if (tid == 0) {
        const float s = (wsum[0] + wsum[1] + wsum[2] + wsum[3]) * inv_norm;
        const unsigned long long contrib =
            (unsigned long long)llrintf(s * FIX_SCALE);
        const unsigned long long old =
            atomicAdd(acc64, (1ULL << CNT_SHIFT) | contrib);
        if ((old >> CNT_SHIFT) == (unsigned long long)(BATCH - 1)) {
            const unsigned long long total = (old & VAL_MASK) + contrib;
            out[0] = (float)((double)total * (double)COEF / (double)FIX_SCALE);
        }
    }
}

extern "C" void kernel_launch(void* const* d_in, const int* in_sizes, int n_in,
                              void* d_out, int out_size, void* d_ws, size_t ws_size,
                              hipStream_t stream) {
    const float* input  = (const float*)d_in[0];
    const int*   target = (const int*)d_in[1];
    float* out = (float*)d_out;
    unsigned long long* acc64 = (unsigned long long*)d_ws;

    // ws is poisoned 0xAA once and never re-poisoned: zero the packed
    // accumulator every call via a trivial kernel node (NOT a memset node —
    // rocclr fill nodes cost ~40-75 us in graph replay, measured round 3).
    dfal_zero_kernel<<<1, 1, 0, stream>>>(acc64);

    dfal_fused2_kernel<<<BATCH, NT, 0, stream>>>(input, target, acc64, out);
}

// Round 5
// 33.494 us; speedup vs baseline: 2.0485x; 2.0485x over previous
//
#include <hip/hip_runtime.h>

#define BATCH 4096
#define CLEN  8192
#define COEF  0.1f
#define NT    1024
#define RPB   8                      // rows per block
#define NBLK  (BATCH / RPB)          // 512 blocks -> 512 same-address atomics

// Fixed-point packing for the single-atomic cross-block reduce:
//   bits [0,44):  sum of llrint(partial * 2^20)  (max ~5.4e11, 32x headroom)
//   bits [44,..): arrival count (each block adds 1<<44; max 512)
#define FIX_SCALE 1048576.0          // 2^20
#define CNT_SHIFT 44
#define VAL_MASK  ((1ULL << CNT_SHIFT) - 1ULL)

// Tiny reset node (memset node and kernel node measured equal-cost, R3/R4).
__global__ void dfal_zero_kernel(unsigned long long* __restrict__ acc64) {
    __hip_atomic_store(acc64, 0ULL, __ATOMIC_RELAXED, __HIP_MEMORY_SCOPE_AGENT);
}

// 512 blocks x 1024 threads; block b handles rows [8b, 8b+8).
// Cross-block combine via ONE packed integer atomic per block (~10 ns/op
// serialized at the coherence point -- 4096 of them cost ~38 us in R3/R4,
// 512 cost ~5 us and overlap with straggler blocks).
__global__ __launch_bounds__(NT) void dfal_fused3_kernel(
    const float* __restrict__ in,
    const int*   __restrict__ target,
    unsigned long long* __restrict__ acc64,
    float*       __restrict__ out)
{
    const int b   = blockIdx.x;
    const int tid = threadIdx.x;

    float acc = 0.0f;
#pragma unroll 2
    for (int r = 0; r < RPB; ++r) {
        const int row = b * RPB + r;
        const long long t = (long long)target[row];
        // Exact sum of squared distances sum_{i=0}^{C-1} (i-t)^2, closed form.
        const long long m  = (long long)(CLEN - 1) - t;
        const long long ss = t * (t + 1) * (2 * t + 1) / 6
                           + m * (m + 1) * (2 * m + 1) / 6;
        const float inv_norm = (t == 0) ? 0.0f : (float)(1.0 / sqrt((double)ss));
        const float tf = (float)t;
        const float4* __restrict__ in4 = (const float4*)(in + (size_t)row * CLEN);

        float p = 0.0f;
#pragma unroll
        for (int k = 0; k < 2; ++k) {
            const int j = tid + k * NT;
            const float4 x = in4[j];
            const float i0 = (float)(4 * j);
            p = fmaf(fabsf(i0        - tf), __expf(x.x), p);
            p = fmaf(fabsf(i0 + 1.0f - tf), __expf(x.y), p);
            p = fmaf(fabsf(i0 + 2.0f - tf), __expf(x.z), p);
            p = fmaf(fabsf(i0 + 3.0f - tf), __expf(x.w), p);
        }
        acc = fmaf(inv_norm, p, acc);   // per-row scale, fixed order
    }

    // Wave (64-lane) reduction, then cross-wave via LDS (16 waves).
#pragma unroll
    for (int off = 32; off; off >>= 1) acc += __shfl_down(acc, off, 64);

    __shared__ float wsum[NT / 64];
    if ((tid & 63) == 0) wsum[tid >> 6] = acc;
    __syncthreads();

    if (tid == 0) {
        float s = 0.0f;
#pragma unroll
        for (int w = 0; w < NT / 64; ++w) s += wsum[w];

        const unsigned long long contrib =
            (unsigned long long)llrint((double)s * FIX_SCALE);
        const unsigned long long old =
            atomicAdd(acc64, (1ULL << CNT_SHIFT) | contrib);
        if ((old >> CNT_SHIFT) == (unsigned long long)(NBLK - 1)) {
            // Our add completed the count: old's value field + our contrib
            // is the full sum. Integer adds commute -> deterministic.
            const unsigned long long total = (old & VAL_MASK) + contrib;
            out[0] = (float)((double)total * (double)COEF / FIX_SCALE);
        }
    }
}

extern "C" void kernel_launch(void* const* d_in, const int* in_sizes, int n_in,
                              void* d_out, int out_size, void* d_ws, size_t ws_size,
                              hipStream_t stream) {
    const float* input  = (const float*)d_in[0];
    const int*   target = (const int*)d_in[1];
    float* out = (float*)d_out;
    unsigned long long* acc64 = (unsigned long long*)d_ws;

    // ws is poisoned 0xAA once and never re-poisoned: zero the packed
    // accumulator every call (graph-capture-legal kernel node).
    dfal_zero_kernel<<<1, 1, 0, stream>>>(acc64);

    dfal_fused3_kernel<<<NBLK, NT, 0, stream>>>(input, target, acc64, out);
}

// Round 7
// 27.317 us; speedup vs baseline: 2.5117x; 1.2261x over previous
//
#include <hip/hip_runtime.h>

#define BATCH 4096
#define CLEN  8192
#define COEF  0.1f
#define NT    256
#define RPB   2                      // rows per block
#define NBLK  (BATCH / RPB)          // 2048 blocks, 8/CU -> 32 waves/CU

// Phase 1: block b computes ws[b] = sum over its RPB rows of
//   inv_norm(t_row) * sum_i |i - t_row| * exp(x[row,i])
// Plain stores, fixed-order arithmetic, no atomics, no reset.
__global__ __launch_bounds__(NT) void dfal_rows_kernel(
    const float* __restrict__ in,
    const int*   __restrict__ target,
    float*       __restrict__ ws)
{
    const int b   = blockIdx.x;
    const int tid = threadIdx.x;

    float acc = 0.0f;
#pragma unroll
    for (int r = 0; r < RPB; ++r) {
        const int row = b * RPB + r;
        const long long t = (long long)target[row];
        // Exact sum of squared distances sum_{i=0}^{C-1} (i-t)^2, closed form.
        const long long m  = (long long)(CLEN - 1) - t;
        const long long ss = t * (t + 1) * (2 * t + 1) / 6
                           + m * (m + 1) * (2 * m + 1) / 6;
        const float inv_norm = (t == 0) ? 0.0f : (float)(1.0 / sqrt((double)ss));
        const float tf = (float)t;
        const float4* __restrict__ in4 = (const float4*)(in + (size_t)row * CLEN);

        float p = 0.0f;
#pragma unroll
        for (int k = 0; k < 8; ++k) {       // round-1-proven: 8 float4/thread/row
            const int j = tid + k * NT;
            const float4 x = in4[j];
            const float i0 = (float)(4 * j);
            p = fmaf(fabsf(i0        - tf), __expf(x.x), p);
            p = fmaf(fabsf(i0 + 1.0f - tf), __expf(x.y), p);
            p = fmaf(fabsf(i0 + 2.0f - tf), __expf(x.z), p);
            p = fmaf(fabsf(i0 + 3.0f - tf), __expf(x.w), p);
        }
        acc = fmaf(inv_norm, p, acc);       // per-row scale, fixed order
    }

    // Wave (64-lane) reduction, then cross-wave via LDS.
#pragma unroll
    for (int off = 32; off; off >>= 1) acc += __shfl_down(acc, off, 64);

    __shared__ float wsum[NT / 64];
    if ((tid & 63) == 0) wsum[tid >> 6] = acc;
    __syncthreads();
    if (tid == 0) ws[b] = wsum[0] + wsum[1] + wsum[2] + wsum[3];
}

// Phase 2: one wave, no LDS, no syncthreads. 2048 floats (8 KB) -> scalar.
__global__ __launch_bounds__(64) void dfal_final_kernel(
    const float* __restrict__ ws,
    float*       __restrict__ out)
{
    const int tid = threadIdx.x;
    float s = 0.0f;
#pragma unroll
    for (int i = 0; i < NBLK / 64; ++i)     // 32 per lane, fixed order
        s += ws[tid + i * 64];
#pragma unroll
    for (int off = 32; off; off >>= 1) s += __shfl_down(s, off, 64);
    if (tid == 0) out[0] = s * COEF;
}

extern "C" void kernel_launch(void* const* d_in, const int* in_sizes, int n_in,
                              void* d_out, int out_size, void* d_ws, size_t ws_size,
                              hipStream_t stream) {
    const float* input  = (const float*)d_in[0];
    const int*   target = (const int*)d_in[1];
    float* out = (float*)d_out;
    float* ws  = (float*)d_ws;   // NBLK floats, fully rewritten every call

    dfal_rows_kernel<<<NBLK, NT, 0, stream>>>(input, target, ws);
    dfal_final_kernel<<<1, 64, 0, stream>>>(ws, out);
}

// Round 9
// 25.778 us; speedup vs baseline: 2.6617x; 1.0597x over previous
//
#include <hip/hip_runtime.h>

#define BATCH 4096
#define CLEN  8192
#define COEF  0.1f
#define NT    256
#define RPB   2                      // rows per block
#define NBLK  (BATCH / RPB)          // 2048 blocks, 8/CU -> 32 waves/CU

// Native clang vector type: __builtin_nontemporal_load requires a pointer to
// scalar/vector-of-scalar, not HIP_vector_type (a struct).
typedef float f32x4 __attribute__((ext_vector_type(4)));

// Phase 1: block b computes ws[b] = sum over its RPB rows of
//   inv_norm(t_row) * sum_i |i - t_row| * exp(x[row,i])
// Identical to round 7 except loads are nontemporal (nt bit: L1 bypass,
// L2 evict-first) -- streaming data with zero reuse.
__global__ __launch_bounds__(NT) void dfal_rows_kernel(
    const float* __restrict__ in,
    const int*   __restrict__ target,
    float*       __restrict__ ws)
{
    const int b   = blockIdx.x;
    const int tid = threadIdx.x;

    float acc = 0.0f;
#pragma unroll
    for (int r = 0; r < RPB; ++r) {
        const int row = b * RPB + r;
        const long long t = (long long)target[row];
        // Exact sum of squared distances sum_{i=0}^{C-1} (i-t)^2, closed form.
        const long long m  = (long long)(CLEN - 1) - t;
        const long long ss = t * (t + 1) * (2 * t + 1) / 6
                           + m * (m + 1) * (2 * m + 1) / 6;
        const float inv_norm = (t == 0) ? 0.0f : (float)(1.0 / sqrt((double)ss));
        const float tf = (float)t;
        const f32x4* __restrict__ in4 = (const f32x4*)(in + (size_t)row * CLEN);

        float p = 0.0f;
#pragma unroll
        for (int k = 0; k < 8; ++k) {       // 8 float4/thread/row, coalesced
            const int j = tid + k * NT;
            const f32x4 x = __builtin_nontemporal_load(&in4[j]);
            const float i0 = (float)(4 * j);
            p = fmaf(fabsf(i0        - tf), __expf(x.x), p);
            p = fmaf(fabsf(i0 + 1.0f - tf), __expf(x.y), p);
            p = fmaf(fabsf(i0 + 2.0f - tf), __expf(x.z), p);
            p = fmaf(fabsf(i0 + 3.0f - tf), __expf(x.w), p);
        }
        acc = fmaf(inv_norm, p, acc);       // per-row scale, fixed order
    }

    // Wave (64-lane) reduction, then cross-wave via LDS.
#pragma unroll
    for (int off = 32; off; off >>= 1) acc += __shfl_down(acc, off, 64);

    __shared__ float wsum[NT / 64];
    if ((tid & 63) == 0) wsum[tid >> 6] = acc;
    __syncthreads();
    if (tid == 0) ws[b] = wsum[0] + wsum[1] + wsum[2] + wsum[3];
}

// Phase 2: one wave, no LDS, no syncthreads. 2048 floats (8 KB) -> scalar.
__global__ __launch_bounds__(64) void dfal_final_kernel(
    const float* __restrict__ ws,
    float*       __restrict__ out)
{
    const int tid = threadIdx.x;
    float s = 0.0f;
#pragma unroll
    for (int i = 0; i < NBLK / 64; ++i)     // 32 per lane, fixed order
        s += ws[tid + i * 64];
#pragma unroll
    for (int off = 32; off; off >>= 1) s += __shfl_down(s, off, 64);
    if (tid == 0) out[0] = s * COEF;
}

extern "C" void kernel_launch(void* const* d_in, const int* in_sizes, int n_in,
                              void* d_out, int out_size, void* d_ws, size_t ws_size,
                              hipStream_t stream) {
    const float* input  = (const float*)d_in[0];
    const int*   target = (const int*)d_in[1];
    float* out = (float*)d_out;
    float* ws  = (float*)d_ws;   // NBLK floats, fully rewritten every call

    dfal_rows_kernel<<<NBLK, NT, 0, stream>>>(input, target, ws);
    dfal_final_kernel<<<1, 64, 0, stream>>>(ws, out);
}

// Round 10
// 25.380 us; speedup vs baseline: 2.7034x; 1.0157x over previous
//
#include <hip/hip_runtime.h>

#define BATCH 4096
#define CLEN  8192
#define COEF  0.1f
#define NT    256
#define RPB   2                      // rows per block
#define NBLK  (BATCH / RPB)          // 2048 blocks, 8/CU -> 32 waves/CU

// Native clang vector type: __builtin_nontemporal_load requires a pointer to
// scalar/vector-of-scalar, not HIP_vector_type (a struct).
typedef float f32x4 __attribute__((ext_vector_type(4)));

// Phase 1: block b computes ws[b] = sum over its 2 rows of
//   inv_norm(t_row) * sum_i |i - t_row| * exp(x[row,i])
// Round-9 + one change: the two rows' loads are INTERLEAVED per k (back-to-
// back issue) so each wave always has >=2 nontemporal loads in flight,
// independent of compiler cross-iteration scheduling.
__global__ __launch_bounds__(NT) void dfal_rows_kernel(
    const float* __restrict__ in,
    const int*   __restrict__ target,
    float*       __restrict__ ws)
{
    const int b   = blockIdx.x;
    const int tid = threadIdx.x;

    const int row0 = b * RPB;
    const int row1 = row0 + 1;

    const long long t0 = (long long)target[row0];
    const long long t1 = (long long)target[row1];

    // Exact sum of squared distances sum_{i=0}^{C-1} (i-t)^2, closed form.
    const long long m0  = (long long)(CLEN - 1) - t0;
    const long long ss0 = t0 * (t0 + 1) * (2 * t0 + 1) / 6
                        + m0 * (m0 + 1) * (2 * m0 + 1) / 6;
    const float inv_norm0 = (t0 == 0) ? 0.0f : (float)(1.0 / sqrt((double)ss0));
    const long long m1  = (long long)(CLEN - 1) - t1;
    const long long ss1 = t1 * (t1 + 1) * (2 * t1 + 1) / 6
                        + m1 * (m1 + 1) * (2 * m1 + 1) / 6;
    const float inv_norm1 = (t1 == 0) ? 0.0f : (float)(1.0 / sqrt((double)ss1));

    const float tf0 = (float)t0;
    const float tf1 = (float)t1;
    const f32x4* __restrict__ inA = (const f32x4*)(in + (size_t)row0 * CLEN);
    const f32x4* __restrict__ inB = (const f32x4*)(in + (size_t)row1 * CLEN);

    float p0 = 0.0f, p1 = 0.0f;
#pragma unroll
    for (int k = 0; k < 8; ++k) {           // 2 x 8 float4/thread, coalesced
        const int j = tid + k * NT;
        const f32x4 xa = __builtin_nontemporal_load(&inA[j]);
        const f32x4 xb = __builtin_nontemporal_load(&inB[j]);
        const float i0 = (float)(4 * j);
        p0 = fmaf(fabsf(i0        - tf0), __expf(xa.x), p0);
        p0 = fmaf(fabsf(i0 + 1.0f - tf0), __expf(xa.y), p0);
        p0 = fmaf(fabsf(i0 + 2.0f - tf0), __expf(xa.z), p0);
        p0 = fmaf(fabsf(i0 + 3.0f - tf0), __expf(xa.w), p0);
        p1 = fmaf(fabsf(i0        - tf1), __expf(xb.x), p1);
        p1 = fmaf(fabsf(i0 + 1.0f - tf1), __expf(xb.y), p1);
        p1 = fmaf(fabsf(i0 + 2.0f - tf1), __expf(xb.z), p1);
        p1 = fmaf(fabsf(i0 + 3.0f - tf1), __expf(xb.w), p1);
    }
    // Per-row scale, fixed order (same arithmetic as round 9).
    float acc = fmaf(inv_norm1, p1, inv_norm0 * p0);

    // Wave (64-lane) reduction, then cross-wave via LDS.
#pragma unroll
    for (int off = 32; off; off >>= 1) acc += __shfl_down(acc, off, 64);

    __shared__ float wsum[NT / 64];
    if ((tid & 63) == 0) wsum[tid >> 6] = acc;
    __syncthreads();
    if (tid == 0) ws[b] = wsum[0] + wsum[1] + wsum[2] + wsum[3];
}

// Phase 2: one wave, no LDS, no syncthreads. 2048 floats (8 KB) -> scalar.
__global__ __launch_bounds__(64) void dfal_final_kernel(
    const float* __restrict__ ws,
    float*       __restrict__ out)
{
    const int tid = threadIdx.x;
    float s = 0.0f;
#pragma unroll
    for (int i = 0; i < NBLK / 64; ++i)     // 32 per lane, fixed order
        s += ws[tid + i * 64];
#pragma unroll
    for (int off = 32; off; off >>= 1) s += __shfl_down(s, off, 64);
    if (tid == 0) out[0] = s * COEF;
}

extern "C" void kernel_launch(void* const* d_in, const int* in_sizes, int n_in,
                              void* d_out, int out_size, void* d_ws, size_t ws_size,
                              hipStream_t stream) {
    const float* input  = (const float*)d_in[0];
    const int*   target = (const int*)d_in[1];
    float* out = (float*)d_out;
    float* ws  = (float*)d_ws;   // NBLK floats, fully rewritten every call

    dfal_rows_kernel<<<NBLK, NT, 0, stream>>>(input, target, ws);
    dfal_final_kernel<<<1, 64, 0, stream>>>(ws, out);
}